// Round 4
// baseline (253.231 us; speedup 1.0000x reference)
//
#include <hip/hip_runtime.h>
#include <hip/hip_bf16.h>

#define BATCH 8
#define NSEQ 1024
#define DIMM 448
#define NHEAD 7
#define HDIM 64
#define MROWS (BATCH*NSEQ)   // 8192
#define KDIM 448
#define SCALE_F 0.125f

typedef short short8 __attribute__((ext_vector_type(8)));
typedef float floatx16 __attribute__((ext_vector_type(16)));

#define MFMA32(a,b,c) __builtin_amdgcn_mfma_f32_32x32x16_bf16(a,b,c,0,0,0)

__device__ __forceinline__ unsigned short f2bf(float f){
    __hip_bfloat16 h = __float2bfloat16(f);
    return *reinterpret_cast<unsigned short*>(&h);
}
__device__ __forceinline__ float bf2f(unsigned short u){
    __hip_bfloat16 h; *reinterpret_cast<unsigned short*>(&h) = u;
    return __bfloat162float(h);
}
__device__ __forceinline__ void gl16(const unsigned short* g, unsigned short* l){
    __builtin_amdgcn_global_load_lds(
        (const __attribute__((address_space(1))) void*)g,
        (__attribute__((address_space(3))) void*)l, 16, 0, 0);
}

// ---------------------------------------------------------------------------
// split fp32 array -> bf16 hi/lo arrays (layout preserved). 1 float4/thread.
// ---------------------------------------------------------------------------
__global__ __launch_bounds__(256)
void split_x(const float* __restrict__ in, unsigned short* __restrict__ hi,
             unsigned short* __restrict__ lo)
{
    int i = blockIdx.x*256 + threadIdx.x;
    float4 v = ((const float4*)in)[i];
    ushort4 h, l;
    h.x = f2bf(v.x); l.x = f2bf(v.x - bf2f(h.x));
    h.y = f2bf(v.y); l.y = f2bf(v.y - bf2f(h.y));
    h.z = f2bf(v.z); l.z = f2bf(v.z - bf2f(h.z));
    h.w = f2bf(v.w); l.w = f2bf(v.w - bf2f(h.w));
    ((ushort4*)hi)[i] = h; ((ushort4*)lo)[i] = l;
}

// ---------------------------------------------------------------------------
// split + transpose weights: W[448][Nsrc] fp32 -> Th/Tl [Nrows][448] bf16
// ---------------------------------------------------------------------------
__global__ __launch_bounds__(64)
void split_wT(const float* __restrict__ W, unsigned short* __restrict__ Th,
              unsigned short* __restrict__ Tl, int Nsrc)
{
    const int kc = blockIdx.x;
    const int n  = blockIdx.y*64 + threadIdx.x;
    ushort4 h0={0,0,0,0}, h1={0,0,0,0}, l0={0,0,0,0}, l1={0,0,0,0};
    if (n < Nsrc) {
        unsigned short h[8], l[8];
#pragma unroll
        for (int j = 0; j < 8; ++j) {
            float f = W[(size_t)(kc*8+j)*Nsrc + n];
            h[j] = f2bf(f); l[j] = f2bf(f - bf2f(h[j]));
        }
        h0 = make_ushort4(h[0],h[1],h[2],h[3]); h1 = make_ushort4(h[4],h[5],h[6],h[7]);
        l0 = make_ushort4(l[0],l[1],l[2],l[3]); l1 = make_ushort4(l[4],l[5],l[6],l[7]);
    }
    size_t o = (size_t)n*KDIM + kc*8;
    *(ushort4*)(Th + o) = h0; *(ushort4*)(Th + o + 4) = h1;
    *(ushort4*)(Tl + o) = l0; *(ushort4*)(Tl + o + 4) = l1;
}

// ---------------------------------------------------------------------------
// bias prep: eb[h][q][m] fp32 -> bp[h][qt][mt][granule] pre-scaled by 0.125,
// granule order = attn's per-lane D-fragment order:
//   granule gr in [0,1024): q = gr&127, seg = gr>>7, elems m = (seg>>1)*8+(seg&1)*4+i
// grid (32 mt, 8 qt, 7 h), block 256
// ---------------------------------------------------------------------------
__global__ __launch_bounds__(256)
void bias_prep(const float* __restrict__ eb, float* __restrict__ bp)
{
    __shared__ float T[128][33];
    const int mt = blockIdx.x, qt = blockIdx.y, h = blockIdx.z;
    const int tid = threadIdx.x;
    const int rq = tid >> 3, rm = (tid & 7) * 4;
#pragma unroll
    for (int it = 0; it < 4; ++it) {
        float4 v = *(const float4*)(eb + ((size_t)(h*NSEQ + qt*128 + it*32 + rq))*NSEQ
                                       + mt*32 + rm);
        T[it*32+rq][rm+0] = v.x; T[it*32+rq][rm+1] = v.y;
        T[it*32+rq][rm+2] = v.z; T[it*32+rq][rm+3] = v.w;
    }
    __syncthreads();
    float* dst = bp + (((size_t)h*8 + qt)*32 + mt)*4096;
#pragma unroll
    for (int it = 0; it < 4; ++it) {
        int gr = it*256 + tid;
        int q = gr & 127, seg = gr >> 7;
        int mb = (seg>>1)*8 + (seg&1)*4;
        float4 v = make_float4(T[q][mb]*SCALE_F, T[q][mb+1]*SCALE_F,
                               T[q][mb+2]*SCALE_F, T[q][mb+3]*SCALE_F);
        *(float4*)(dst + (size_t)gr*4) = v;
    }
}

// ---------------------------------------------------------------------------
// Split-2 bf16 MFMA GEMM, double-buffered gl16 staging (1 barrier / k-tile).
// mode 0: emit q hi/lo [b][h][n][d] bf16 and vT hi/lo [b][h][d][n] bf16
// mode 1: out(fp32) = C + bias, n >= 448 masked
// ---------------------------------------------------------------------------
__global__ __launch_bounds__(256)
void gemm_bf(const unsigned short* __restrict__ Ah, const unsigned short* __restrict__ Al,
             const unsigned short* __restrict__ Bh, const unsigned short* __restrict__ Bl,
             const float* __restrict__ bias, void* __restrict__ o0, void* __restrict__ o1,
             void* __restrict__ o2, void* __restrict__ o3, int mode)
{
    __shared__ unsigned short sAh[2][4096], sAl[2][4096], sBh[2][4096], sBl[2][4096];

    const int tid  = threadIdx.x;
    const int lane = tid & 63;
    const int w    = tid >> 6;
    const int lq   = lane & 31;
    const int lh   = lane >> 5;
    const int wm   = (w >> 1) * 64;
    const int wn   = (w & 1) * 64;
    const int m0   = blockIdx.x * 128;
    const int n0   = blockIdx.y * 128;

    const int srow = tid & 127;
    const int skh  = (tid >> 7) & 1;
    const unsigned short* pAh = Ah + (size_t)(m0 + srow)*KDIM + skh*8;
    const unsigned short* pAl = Al + (size_t)(m0 + srow)*KDIM + skh*8;
    const unsigned short* pBh = Bh + (size_t)(n0 + srow)*KDIM + skh*8;
    const unsigned short* pBl = Bl + (size_t)(n0 + srow)*KDIM + skh*8;

#define GSTAGE(kt, bf) { const int k0 = (kt)*32;                       \
        gl16(pAh + k0,      &sAh[bf][tid*8]);                          \
        gl16(pAh + k0 + 16, &sAh[bf][2048 + tid*8]);                   \
        gl16(pAl + k0,      &sAl[bf][tid*8]);                          \
        gl16(pAl + k0 + 16, &sAl[bf][2048 + tid*8]);                   \
        gl16(pBh + k0,      &sBh[bf][tid*8]);                          \
        gl16(pBh + k0 + 16, &sBh[bf][2048 + tid*8]);                   \
        gl16(pBl + k0,      &sBl[bf][tid*8]);                          \
        gl16(pBl + k0 + 16, &sBl[bf][2048 + tid*8]); }

    floatx16 acc[2][2] = {};

    GSTAGE(0, 0)
    for (int kt = 0; kt < 14; ++kt) {
        __syncthreads();
        if (kt < 13) GSTAGE(kt+1, (kt+1)&1)
        const int buf = kt & 1;
#pragma unroll
        for (int c = 0; c < 2; ++c) {
            const int gb = (c*2 + lh)*128;
            short8 a_h[2], a_l[2], b_h[2], b_l[2];
#pragma unroll
            for (int f = 0; f < 2; ++f) {
                a_h[f] = *(const short8*)&sAh[buf][(size_t)(gb + wm + f*32 + lq)*8];
                a_l[f] = *(const short8*)&sAl[buf][(size_t)(gb + wm + f*32 + lq)*8];
                b_h[f] = *(const short8*)&sBh[buf][(size_t)(gb + wn + f*32 + lq)*8];
                b_l[f] = *(const short8*)&sBl[buf][(size_t)(gb + wn + f*32 + lq)*8];
            }
#pragma unroll
            for (int fm = 0; fm < 2; ++fm)
#pragma unroll
                for (int fn = 0; fn < 2; ++fn) {
                    acc[fm][fn] = MFMA32(a_h[fm], b_h[fn], acc[fm][fn]);
                    acc[fm][fn] = MFMA32(a_l[fm], b_h[fn], acc[fm][fn]);
                    acc[fm][fn] = MFMA32(a_h[fm], b_l[fn], acc[fm][fn]);
                }
        }
    }
#undef GSTAGE

    if (mode == 0) {
        unsigned short* qh = (unsigned short*)o0;
        unsigned short* ql = (unsigned short*)o1;
        unsigned short* vTh = (unsigned short*)o2;
        unsigned short* vTl = (unsigned short*)o3;
#pragma unroll
        for (int fm = 0; fm < 2; ++fm)
#pragma unroll
            for (int fn = 0; fn < 2; ++fn) {
                const int gn = n0 + wn + fn*32 + lq;
                const int hb = gn >> 6, d = gn & 63;
#pragma unroll
                for (int r = 0; r < 16; ++r) {
                    const int gm = m0 + wm + fm*32 + ((r&3) + 8*((r>>2)&3) + 4*lh);
                    const int b = gm >> 10, ns = gm & 1023;
                    const float v = acc[fm][fn][r];
                    unsigned short h = f2bf(v), l = f2bf(v - bf2f(h));
                    if (hb < NHEAD) {
                        size_t o = ((size_t)((b*NHEAD + hb)*NSEQ + ns))*HDIM + d;
                        qh[o] = h; ql[o] = l;
                    } else {
                        size_t o = ((size_t)((b*NHEAD + hb - NHEAD)*HDIM + d))*NSEQ + ns;
                        vTh[o] = h; vTl[o] = l;
                    }
                }
            }
    } else {
        float* out = (float*)o0;
#pragma unroll
        for (int fm = 0; fm < 2; ++fm)
#pragma unroll
            for (int fn = 0; fn < 2; ++fn) {
                const int gn = n0 + wn + fn*32 + lq;
                if (gn < DIMM) {
                    const float bv = bias[gn];
#pragma unroll
                    for (int r = 0; r < 16; ++r) {
                        const int gm = m0 + wm + fm*32 + ((r&3) + 8*((r>>2)&3) + 4*lh);
                        out[(size_t)gm*DIMM + gn] = acc[fm][fn][r] + bv;
                    }
                }
            }
    }
}

// ---------------------------------------------------------------------------
// MFMA flash attention, split-2 bf16, no-max softmax (scores bounded).
// All inputs pre-split bf16; K/V staged via double-buffered gl16 (1 barrier/
// tile); bias pre-scaled+granule-ordered, prefetched per-lane into registers.
// ---------------------------------------------------------------------------
__global__ __launch_bounds__(256, 2)
void attn_mfma(const unsigned short* __restrict__ qh_g, const unsigned short* __restrict__ ql_g,
               const unsigned short* __restrict__ vTh, const unsigned short* __restrict__ vTl,
               const unsigned short* __restrict__ ekh, const unsigned short* __restrict__ ekl,
               const float* __restrict__ bp,
               unsigned short* __restrict__ aoh, unsigned short* __restrict__ aol)
{
    __shared__ unsigned short khi[2][2048], klo[2][2048];
    __shared__ unsigned short vhi[2][2048], vlo[2][2048];
    __shared__ unsigned short phi[4][1024], plo[4][1024];
    __shared__ float l_inv[4][32];

    const int tid  = threadIdx.x;
    const int w    = tid >> 6;
    const int lane = tid & 63;
    const int lq   = lane & 31;
    const int lh   = lane >> 5;
    const int head = blockIdx.y, b = blockIdx.z;
    const int qt   = blockIdx.x;
    const int q0   = qt * 128;

    // Q fragments (bf16 hi/lo, direct 16B loads)
    short8 qh[4], ql[4];
    {
        const size_t qrow = ((size_t)((b*NHEAD+head)*NSEQ) + q0 + w*32 + lq)*HDIM;
#pragma unroll
        for (int c = 0; c < 4; ++c) {
            qh[c] = *(const short8*)(qh_g + qrow + c*16 + lh*8);
            ql[c] = *(const short8*)(ql_g + qrow + c*16 + lh*8);
        }
    }

    // staging source pointers (granule id == tid)
    const unsigned short* kH = ekh + ((size_t)head*NSEQ + (tid&31))*HDIM + ((tid>>5)&7)*8;
    const unsigned short* kL = ekl + ((size_t)head*NSEQ + (tid&31))*HDIM + ((tid>>5)&7)*8;
    const unsigned short* vH = vTh + ((size_t)((b*NHEAD+head)*HDIM) + (tid&63))*NSEQ + (tid>>6)*8;
    const unsigned short* vL = vTl + ((size_t)((b*NHEAD+head)*HDIM) + (tid&63))*NSEQ + (tid>>6)*8;
    const float* bbase = bp + (((size_t)head*8 + qt)*32)*4096
                            + (size_t)(lh*128 + w*32 + lq)*4;

#define ASTAGE(mt, bf) {                              \
        gl16(kH + (mt)*2048, &khi[bf][tid*8]);        \
        gl16(kL + (mt)*2048, &klo[bf][tid*8]);        \
        gl16(vH + (mt)*32,   &vhi[bf][tid*8]);        \
        gl16(vL + (mt)*32,   &vlo[bf][tid*8]); }

    floatx16 O0 = {}, O1 = {};
    float lsum = 0.f;

    float4 bcur[4], bnxt[4];
    ASTAGE(0, 0)
#pragma unroll
    for (int g = 0; g < 4; ++g)
        bcur[g] = *(const float4*)(bbase + g*1024);

    for (int mt = 0; mt < 32; ++mt) {
        __syncthreads();                       // tile mt staged (vmcnt drained)
        if (mt < 31) {
            ASTAGE(mt+1, (mt+1)&1)
#pragma unroll
            for (int g = 0; g < 4; ++g)
                bnxt[g] = *(const float4*)(bbase + (size_t)(mt+1)*4096 + g*1024);
        }
        const int buf = mt & 1;

        // ---- S = K . Q (split-2) ----
        floatx16 S = {};
#pragma unroll
        for (int c = 0; c < 4; ++c) {
            short8 ah = *(const short8*)&khi[buf][((c*2+lh)*32 + lq)*8];
            short8 al = *(const short8*)&klo[buf][((c*2+lh)*32 + lq)*8];
            S = MFMA32(ah, qh[c], S);
            S = MFMA32(ah, ql[c], S);
            S = MFMA32(al, qh[c], S);
        }

        // ---- p = exp(fma(S, scale, bias')) ; P (split) -> per-wave LDS ----
        unsigned short* pwh = phi[w];
        unsigned short* pwl = plo[w];
#pragma unroll
        for (int g = 0; g < 4; ++g) {
            float pv[4];
            pv[0] = __expf(fmaf(S[4*g+0], SCALE_F, bcur[g].x));
            pv[1] = __expf(fmaf(S[4*g+1], SCALE_F, bcur[g].y));
            pv[2] = __expf(fmaf(S[4*g+2], SCALE_F, bcur[g].z));
            pv[3] = __expf(fmaf(S[4*g+3], SCALE_F, bcur[g].w));
            lsum += pv[0] + pv[1] + pv[2] + pv[3];
            unsigned short hb[4], lb[4];
#pragma unroll
            for (int i = 0; i < 4; ++i) {
                hb[i] = f2bf(pv[i]);
                lb[i] = f2bf(pv[i] - bf2f(hb[i]));
            }
            *(ushort4*)(pwh + g*256 + lq*8 + lh*4) = make_ushort4(hb[0],hb[1],hb[2],hb[3]);
            *(ushort4*)(pwl + g*256 + lq*8 + lh*4) = make_ushort4(lb[0],lb[1],lb[2],lb[3]);
        }

        // ---- O += P . V (split-2) ----
#pragma unroll
        for (int c2 = 0; c2 < 2; ++c2) {
            short8 ah  = *(const short8*)(pwh + ((c2*2+lh)*32 + lq)*8);
            short8 al  = *(const short8*)(pwl + ((c2*2+lh)*32 + lq)*8);
            short8 bh0 = *(const short8*)&vhi[buf][((c2*2+lh)*64 +      lq)*8];
            short8 bl0 = *(const short8*)&vlo[buf][((c2*2+lh)*64 +      lq)*8];
            short8 bh1 = *(const short8*)&vhi[buf][((c2*2+lh)*64 + 32 + lq)*8];
            short8 bl1 = *(const short8*)&vlo[buf][((c2*2+lh)*64 + 32 + lq)*8];
            O0 = MFMA32(ah, bh0, O0);
            O0 = MFMA32(al, bh0, O0);
            O0 = MFMA32(ah, bl0, O0);
            O1 = MFMA32(ah, bh1, O1);
            O1 = MFMA32(al, bh1, O1);
            O1 = MFMA32(ah, bl1, O1);
        }

        if (mt < 31) {
#pragma unroll
            for (int g = 0; g < 4; ++g) bcur[g] = bnxt[g];
        }
    }
#undef ASTAGE

    float ltot = lsum + __shfl_xor(lsum, 32);
    if (lh == 0) l_inv[w][lq] = 1.0f / ltot;
    __syncthreads();

    const size_t obase = ((size_t)(b*NSEQ + q0 + w*32))*DIMM + head*HDIM;
#pragma unroll
    for (int r = 0; r < 16; ++r) {
        int qr = (r&3) + 8*(r>>2) + 4*lh;
        float inv = l_inv[w][qr];
        float v0 = O0[r]*inv, v1 = O1[r]*inv;
        unsigned short h0 = f2bf(v0), h1 = f2bf(v1);
        size_t o = obase + (size_t)qr*DIMM + lq;
        aoh[o]      = h0;  aol[o]      = f2bf(v0 - bf2f(h0));
        aoh[o + 32] = h1;  aol[o + 32] = f2bf(v1 - bf2f(h1));
    }
}

// ---------------------------------------------------------------------------
extern "C" void kernel_launch(void* const* d_in, const int* in_sizes, int n_in,
                              void* d_out, int out_size, void* d_ws, size_t ws_size,
                              hipStream_t stream)
{
    const float* x    = (const float*)d_in[0];
    const float* wqv  = (const float*)d_in[1];
    const float* ek   = (const float*)d_in[2];
    const float* eb   = (const float*)d_in[3];
    const float* wout = (const float*)d_in[4];
    const float* bout = (const float*)d_in[5];
    float* out = (float*)d_out;

    const size_t MK = (size_t)MROWS*KDIM;     // 3,670,016
    const size_t EK = (size_t)NHEAD*NSEQ*HDIM; // 458,752
    unsigned short* p = (unsigned short*)d_ws;
    unsigned short* xh    = p;                 p += MK;
    unsigned short* xl    = p;                 p += MK;
    unsigned short* wqvTh = p;                 p += (size_t)896*KDIM;
    unsigned short* wqvTl = p;                 p += (size_t)896*KDIM;
    unsigned short* woTh  = p;                 p += (size_t)512*KDIM;
    unsigned short* woTl  = p;                 p += (size_t)512*KDIM;
    unsigned short* qh    = p;                 p += MK;
    unsigned short* ql    = p;                 p += MK;
    unsigned short* vTh   = p;                 p += MK;
    unsigned short* vTl   = p;                 p += MK;
    unsigned short* ekh   = p;                 p += EK;
    unsigned short* ekl   = p;                 p += EK;
    float* biasP = (float*)p;                  // 7,340,032 floats (29.4 MB)
    // ao aliases x-split region (dead after gemm1)
    unsigned short* aoh = xh;
    unsigned short* aol = xl;

    split_x<<<MK/1024, 256, 0, stream>>>(x, xh, xl);
    split_x<<<EK/1024, 256, 0, stream>>>(ek, ekh, ekl);
    split_wT<<<dim3(56, 14), 64, 0, stream>>>(wqv, wqvTh, wqvTl, 896);
    split_wT<<<dim3(56, 8), 64, 0, stream>>>(wout, woTh, woTl, DIMM);
    bias_prep<<<dim3(32, 8, 7), 256, 0, stream>>>(eb, biasP);

    gemm_bf<<<dim3(64, 7), 256, 0, stream>>>(xh, xl, wqvTh, wqvTl, nullptr,
                                             qh, ql, vTh, vTl, 0);
    attn_mfma<<<dim3(8, NHEAD, BATCH), 256, 0, stream>>>(qh, ql, vTh, vTl,
                                                         ekh, ekl, biasP, aoh, aol);
    gemm_bf<<<dim3(64, 4), 256, 0, stream>>>(aoh, aol, woTh, woTl, bout,
                                             out, nullptr, nullptr, nullptr, 1);
}

// Round 5
// 210.559 us; speedup vs baseline: 1.2027x; 1.2027x over previous
//
#include <hip/hip_runtime.h>
#include <hip/hip_bf16.h>
#include <hip/hip_fp16.h>

#define BATCH 8
#define NSEQ 1024
#define DIMM 448
#define NHEAD 7
#define HDIM 64
#define MROWS (BATCH*NSEQ)   // 8192
#define KDIM 448
#define SCALE_F 0.125f

typedef short short8 __attribute__((ext_vector_type(8)));
typedef float floatx16 __attribute__((ext_vector_type(16)));

#define MFMA32(a,b,c) __builtin_amdgcn_mfma_f32_32x32x16_bf16(a,b,c,0,0,0)

__device__ __forceinline__ unsigned short f2bf(float f){
    __hip_bfloat16 h = __float2bfloat16(f);
    return *reinterpret_cast<unsigned short*>(&h);
}
__device__ __forceinline__ float bf2f(unsigned short u){
    __hip_bfloat16 h; *reinterpret_cast<unsigned short*>(&h) = u;
    return __bfloat162float(h);
}
__device__ __forceinline__ float h2f(unsigned short u){
    __half h; *reinterpret_cast<unsigned short*>(&h) = u;
    return __half2float(h);
}
__device__ __forceinline__ unsigned short f2h(float f){
    __half h = __float2half(f);
    return *reinterpret_cast<unsigned short*>(&h);
}
__device__ __forceinline__ void gl16(const unsigned short* g, unsigned short* l){
    __builtin_amdgcn_global_load_lds(
        (const __attribute__((address_space(1))) void*)g,
        (__attribute__((address_space(3))) void*)l, 16, 0, 0);
}

// ---------------------------------------------------------------------------
// fp32 -> single bf16 (layout preserved), 1 float4/thread
// ---------------------------------------------------------------------------
__global__ __launch_bounds__(256)
void cvt_single(const float* __restrict__ in, unsigned short* __restrict__ hi)
{
    int i = blockIdx.x*256 + threadIdx.x;
    float4 v = ((const float4*)in)[i];
    ((ushort4*)hi)[i] = make_ushort4(f2bf(v.x), f2bf(v.y), f2bf(v.z), f2bf(v.w));
}

// ---------------------------------------------------------------------------
// transpose weights to [N][448], single bf16. grid (56, Nrows/64), block 64
// ---------------------------------------------------------------------------
__global__ __launch_bounds__(64)
void wT_single(const float* __restrict__ W, unsigned short* __restrict__ Th, int Nsrc)
{
    const int kc = blockIdx.x;
    const int n  = blockIdx.y*64 + threadIdx.x;
    ushort4 h0={0,0,0,0}, h1={0,0,0,0};
    if (n < Nsrc) {
        unsigned short h[8];
#pragma unroll
        for (int j = 0; j < 8; ++j) h[j] = f2bf(W[(size_t)(kc*8+j)*Nsrc + n]);
        h0 = make_ushort4(h[0],h[1],h[2],h[3]); h1 = make_ushort4(h[4],h[5],h[6],h[7]);
    }
    size_t o = (size_t)n*KDIM + kc*8;
    *(ushort4*)(Th + o) = h0; *(ushort4*)(Th + o + 4) = h1;
}

// ---------------------------------------------------------------------------
// transpose weights to [N][448], split hi/lo (for w_out). rows>=Nsrc zeroed.
// ---------------------------------------------------------------------------
__global__ __launch_bounds__(64)
void split_wT(const float* __restrict__ W, unsigned short* __restrict__ Th,
              unsigned short* __restrict__ Tl, int Nsrc)
{
    const int kc = blockIdx.x;
    const int n  = blockIdx.y*64 + threadIdx.x;
    ushort4 h0={0,0,0,0}, h1={0,0,0,0}, l0={0,0,0,0}, l1={0,0,0,0};
    if (n < Nsrc) {
        unsigned short h[8], l[8];
#pragma unroll
        for (int j = 0; j < 8; ++j) {
            float f = W[(size_t)(kc*8+j)*Nsrc + n];
            h[j] = f2bf(f); l[j] = f2bf(f - bf2f(h[j]));
        }
        h0 = make_ushort4(h[0],h[1],h[2],h[3]); h1 = make_ushort4(h[4],h[5],h[6],h[7]);
        l0 = make_ushort4(l[0],l[1],l[2],l[3]); l1 = make_ushort4(l[4],l[5],l[6],l[7]);
    }
    size_t o = (size_t)n*KDIM + kc*8;
    *(ushort4*)(Th + o) = h0; *(ushort4*)(Th + o + 4) = h1;
    *(ushort4*)(Tl + o) = l0; *(ushort4*)(Tl + o + 4) = l1;
}

// ---------------------------------------------------------------------------
// bias prep: eb[h][q][m] fp32 -> fp16, pre-scaled by 0.125, in per-lane
// granule order for attn (lane t reads 32B at slab + t*16 ushorts).
// grid (32 mt, 16 qt, 7 h), block 128.
// ---------------------------------------------------------------------------
__global__ __launch_bounds__(128)
void bias_prep(const float* __restrict__ eb, unsigned short* __restrict__ bp)
{
    __shared__ float T[64][33];
    const int mt = blockIdx.x, qt = blockIdx.y, h = blockIdx.z;
    const int tid = threadIdx.x;
#pragma unroll
    for (int it = 0; it < 4; ++it) {
        int f4 = it*128 + tid;
        int row = f4 >> 3, c4 = (f4 & 7)*4;
        float4 v = *(const float4*)(eb + ((size_t)(h*NSEQ + qt*64 + row))*NSEQ + mt*32 + c4);
        T[row][c4+0]=v.x; T[row][c4+1]=v.y; T[row][c4+2]=v.z; T[row][c4+3]=v.w;
    }
    __syncthreads();
    const int qloc = (tid>>6)*32 + (tid&31);
    const int lh = (tid>>5)&1;
    unsigned short* dst = bp + (((size_t)h*16 + qt)*32 + mt)*2048 + tid*16;
#pragma unroll
    for (int c = 0; c < 2; ++c) {
        unsigned short o[8];
#pragma unroll
        for (int j = 0; j < 8; ++j) {
            int m = 16*c + 8*(j>>2) + 4*lh + (j&3);
            o[j] = f2h(T[qloc][m] * SCALE_F);
        }
        *(ushort4*)(dst + c*8)     = make_ushort4(o[0],o[1],o[2],o[3]);
        *(ushort4*)(dst + c*8 + 4) = make_ushort4(o[4],o[5],o[6],o[7]);
    }
}

// ---------------------------------------------------------------------------
// gemm1: qv = x @ w_qv, pure single bf16. Tile 64x128, 2 waves, BK=32, dbuf.
// Scatter: q [b][h][n][d] bf16 single; vT [b][h][d][n] bf16 single.
// grid (128, 7), block 128
// ---------------------------------------------------------------------------
__global__ __launch_bounds__(128)
void gemm1(const unsigned short* __restrict__ Ah, const unsigned short* __restrict__ Bh,
           unsigned short* __restrict__ qd, unsigned short* __restrict__ vTd)
{
    __shared__ unsigned short sA[2][2048], sB[2][4096];
    const int tid = threadIdx.x;
    const int lane = tid & 63, w = tid >> 6;
    const int lq = lane & 31, lh = lane >> 5;
    const int m0 = blockIdx.x * 64, n0 = blockIdx.y * 128;

    const unsigned short* pA = Ah + (size_t)(m0 + (tid&63))*KDIM + (tid>>6)*8;
    const unsigned short* pB = Bh + (size_t)(n0 + tid)*KDIM;

#define G1STAGE(kt, bf) { const int k0 = (kt)*32;                 \
        gl16(pA + k0,      &sA[bf][tid*8]);                       \
        gl16(pA + k0 + 16, &sA[bf][(tid+128)*8]);                 \
        gl16(pB + k0,      &sB[bf][tid*8]);                       \
        gl16(pB + k0 + 8,  &sB[bf][(tid+128)*8]);                 \
        gl16(pB + k0 + 16, &sB[bf][(tid+256)*8]);                 \
        gl16(pB + k0 + 24, &sB[bf][(tid+384)*8]); }

    floatx16 acc[4] = {};
    G1STAGE(0, 0)
    for (int kt = 0; kt < 14; ++kt) {
        __syncthreads();
        if (kt < 13) G1STAGE(kt+1, (kt+1)&1)
        const int buf = kt & 1;
#pragma unroll
        for (int c = 0; c < 2; ++c) {
            short8 a = *(const short8*)&sA[buf][((c*2+lh)*64 + w*32 + lq)*8];
#pragma unroll
            for (int fn = 0; fn < 4; ++fn) {
                short8 b = *(const short8*)&sB[buf][((c*2+lh)*128 + fn*32 + lq)*8];
                acc[fn] = MFMA32(a, b, acc[fn]);
            }
        }
    }
#undef G1STAGE

#pragma unroll
    for (int fn = 0; fn < 4; ++fn) {
        const int gn = n0 + fn*32 + lq;
        const int hcol = gn >> 6, d = gn & 63;
#pragma unroll
        for (int r = 0; r < 16; ++r) {
            const int gm = m0 + w*32 + (r&3) + 8*(r>>2) + 4*lh;
            const int b = gm >> 10, ns = gm & 1023;
            unsigned short h = f2bf(acc[fn][r]);
            if (hcol < NHEAD)
                qd[((size_t)((b*NHEAD + hcol)*NSEQ + ns))*HDIM + d] = h;
            else
                vTd[((size_t)((b*NHEAD + hcol - NHEAD)*HDIM + d))*NSEQ + ns] = h;
        }
    }
}

// ---------------------------------------------------------------------------
// attn: single-bf16 Q/K/V/P, fp16 pre-scaled bias, no-max softmax, l via
// MFMA-with-ones. Block 128 thr = 2 waves x 32q (q-tile 64); 2 mt per
// barrier, double-buffered gl16. grid (16 qt, 7 h, 8 b)
// ---------------------------------------------------------------------------
__global__ __launch_bounds__(128)
void attn2(const unsigned short* __restrict__ qh_g, const unsigned short* __restrict__ vTh,
           const unsigned short* __restrict__ ekh, const unsigned short* __restrict__ bp,
           unsigned short* __restrict__ aoh, unsigned short* __restrict__ aol)
{
    __shared__ unsigned short kS[2][2][2048];   // [buf][mt-half][32m x 64d]
    __shared__ unsigned short vS[2][2][2048];   // [buf][mt-half][64d x 32m]
    __shared__ unsigned short pS[2][1024];      // [wave][32q x 32m]

    const int tid = threadIdx.x;
    const int w = tid >> 6, lane = tid & 63;
    const int lq = lane & 31, lh = lane >> 5;
    const int qt = blockIdx.x, head = blockIdx.y, b = blockIdx.z;
    const int q0 = qt * 64;

    // Q fragments (single bf16)
    short8 qf[4];
    {
        const size_t qrow = ((size_t)((b*NHEAD+head)*NSEQ) + q0 + w*32 + lq)*HDIM;
#pragma unroll
        for (int c = 0; c < 4; ++c)
            qf[c] = *(const short8*)(qh_g + qrow + c*16 + lh*8);
    }
    short8 ones;
#pragma unroll
    for (int j = 0; j < 8; ++j) ones[j] = (short)0x3F80;

    const unsigned short* kp0 = ekh + ((size_t)head*NSEQ + (tid&31))*HDIM + (tid>>5)*8;
    const unsigned short* kp1 = kp0 + 32;
    const unsigned short* vp0 = vTh + ((size_t)((b*NHEAD+head)*HDIM) + (tid&63))*NSEQ + (tid>>6)*8;
    const unsigned short* vp1 = vp0 + 16;
    const unsigned short* bptr = bp + (((size_t)head*16 + qt)*32)*2048 + tid*16;

#define ASTAGE(sec, bf) { const int mA = (sec)*2, mB = mA+1;     \
        gl16(kp0 + mA*2048, &kS[bf][0][tid*8]);                  \
        gl16(kp1 + mA*2048, &kS[bf][0][(tid+128)*8]);            \
        gl16(kp0 + mB*2048, &kS[bf][1][tid*8]);                  \
        gl16(kp1 + mB*2048, &kS[bf][1][(tid+128)*8]);            \
        gl16(vp0 + mA*32,   &vS[bf][0][tid*8]);                  \
        gl16(vp1 + mA*32,   &vS[bf][0][(tid+128)*8]);            \
        gl16(vp0 + mB*32,   &vS[bf][1][tid*8]);                  \
        gl16(vp1 + mB*32,   &vS[bf][1][(tid+128)*8]); }
#define BLOAD(sec, dst) {                                             \
        dst[0][0] = *(const short8*)(bptr + (size_t)(2*(sec))*2048);  \
        dst[0][1] = *(const short8*)(bptr + (size_t)(2*(sec))*2048 + 8); \
        dst[1][0] = *(const short8*)(bptr + (size_t)(2*(sec)+1)*2048);   \
        dst[1][1] = *(const short8*)(bptr + (size_t)(2*(sec)+1)*2048 + 8); }

    floatx16 O0 = {}, O1 = {}, Ol = {};
    short8 bc[2][2], bn[2][2];

    ASTAGE(0, 0)
    BLOAD(0, bc)

    for (int sec = 0; sec < 16; ++sec) {
        __syncthreads();                         // drains stage(sec)
        if (sec < 15) {
            ASTAGE(sec+1, (sec+1)&1)
            BLOAD(sec+1, bn)
        }
        const int buf = sec & 1;

#pragma unroll
        for (int hf = 0; hf < 2; ++hf) {
            // ---- S = K . Q  (single) ----
            floatx16 S = {};
#pragma unroll
            for (int c = 0; c < 4; ++c) {
                short8 kf = *(const short8*)&kS[buf][hf][((c*2+lh)*32 + lq)*8];
                S = MFMA32(kf, qf[c], S);
            }
            // ---- p = exp(S*scale + bias'), write single-bf16 P ----
            unsigned short* pw = pS[w];
#pragma unroll
            for (int g = 0; g < 4; ++g) {
                unsigned short hb[4];
#pragma unroll
                for (int j = 0; j < 4; ++j) {
                    const int i = g*4 + j;
                    float bs = h2f((unsigned short)bc[hf][i>>3][i&7]);
                    hb[j] = f2bf(__expf(fmaf(S[i], SCALE_F, bs)));
                }
                *(ushort4*)(pw + g*256 + lq*8 + lh*4) = make_ushort4(hb[0],hb[1],hb[2],hb[3]);
            }
            // ---- O += P.V ; l += P.1 ----
#pragma unroll
            for (int c2 = 0; c2 < 2; ++c2) {
                short8 pf = *(const short8*)(pw + ((c2*2+lh)*32 + lq)*8);
                short8 v0 = *(const short8*)&vS[buf][hf][((c2*2+lh)*64 +      lq)*8];
                short8 v1 = *(const short8*)&vS[buf][hf][((c2*2+lh)*64 + 32 + lq)*8];
                O0 = MFMA32(pf, v0, O0);
                O1 = MFMA32(pf, v1, O1);
                Ol = MFMA32(pf, ones, Ol);
            }
        }
        if (sec < 15) {
#pragma unroll
            for (int hf = 0; hf < 2; ++hf) { bc[hf][0] = bn[hf][0]; bc[hf][1] = bn[hf][1]; }
        }
    }
#undef ASTAGE
#undef BLOAD

    const size_t obase = ((size_t)(b*NSEQ + q0 + w*32))*DIMM + head*HDIM;
#pragma unroll
    for (int r = 0; r < 16; ++r) {
        const int qr = (r&3) + 8*(r>>2) + 4*lh;
        const float inv = 1.0f / Ol[r];
        float v0 = O0[r]*inv, v1 = O1[r]*inv;
        unsigned short h0 = f2bf(v0), h1 = f2bf(v1);
        size_t o = obase + (size_t)qr*DIMM + lq;
        aoh[o]      = h0;  aol[o]      = f2bf(v0 - bf2f(h0));
        aoh[o + 32] = h1;  aol[o + 32] = f2bf(v1 - bf2f(h1));
    }
}

// ---------------------------------------------------------------------------
// gemm2: out = ao @ w_out + b_out, 3-term split-2 (accuracy-critical).
// Tile 64x128, 2 waves, BK=32, dbuf. grid (128, 4), block 128
// ---------------------------------------------------------------------------
__global__ __launch_bounds__(128)
void gemm2(const unsigned short* __restrict__ Ah, const unsigned short* __restrict__ Al,
           const unsigned short* __restrict__ Bh, const unsigned short* __restrict__ Bl,
           const float* __restrict__ bias, float* __restrict__ out)
{
    __shared__ unsigned short sAh[2][2048], sAl[2][2048], sBh[2][4096], sBl[2][4096];
    const int tid = threadIdx.x;
    const int lane = tid & 63, w = tid >> 6;
    const int lq = lane & 31, lh = lane >> 5;
    const int m0 = blockIdx.x * 64, n0 = blockIdx.y * 128;

    const unsigned short* pAh = Ah + (size_t)(m0 + (tid&63))*KDIM + (tid>>6)*8;
    const unsigned short* pAl = Al + (size_t)(m0 + (tid&63))*KDIM + (tid>>6)*8;
    const unsigned short* pBh = Bh + (size_t)(n0 + tid)*KDIM;
    const unsigned short* pBl = Bl + (size_t)(n0 + tid)*KDIM;

#define G2STAGE(kt, bf) { const int k0 = (kt)*32;                 \
        gl16(pAh + k0,      &sAh[bf][tid*8]);                     \
        gl16(pAh + k0 + 16, &sAh[bf][(tid+128)*8]);               \
        gl16(pAl + k0,      &sAl[bf][tid*8]);                     \
        gl16(pAl + k0 + 16, &sAl[bf][(tid+128)*8]);               \
        gl16(pBh + k0,      &sBh[bf][tid*8]);                     \
        gl16(pBh + k0 + 8,  &sBh[bf][(tid+128)*8]);               \
        gl16(pBh + k0 + 16, &sBh[bf][(tid+256)*8]);               \
        gl16(pBh + k0 + 24, &sBh[bf][(tid+384)*8]);               \
        gl16(pBl + k0,      &sBl[bf][tid*8]);                     \
        gl16(pBl + k0 + 8,  &sBl[bf][(tid+128)*8]);               \
        gl16(pBl + k0 + 16, &sBl[bf][(tid+256)*8]);               \
        gl16(pBl + k0 + 24, &sBl[bf][(tid+384)*8]); }

    floatx16 acc[4] = {};
    G2STAGE(0, 0)
    for (int kt = 0; kt < 14; ++kt) {
        __syncthreads();
        if (kt < 13) G2STAGE(kt+1, (kt+1)&1)
        const int buf = kt & 1;
#pragma unroll
        for (int c = 0; c < 2; ++c) {
            short8 ah = *(const short8*)&sAh[buf][((c*2+lh)*64 + w*32 + lq)*8];
            short8 al = *(const short8*)&sAl[buf][((c*2+lh)*64 + w*32 + lq)*8];
#pragma unroll
            for (int fn = 0; fn < 4; ++fn) {
                short8 bh = *(const short8*)&sBh[buf][((c*2+lh)*128 + fn*32 + lq)*8];
                short8 bl = *(const short8*)&sBl[buf][((c*2+lh)*128 + fn*32 + lq)*8];
                acc[fn] = MFMA32(ah, bh, acc[fn]);
                acc[fn] = MFMA32(al, bh, acc[fn]);
                acc[fn] = MFMA32(ah, bl, acc[fn]);
            }
        }
    }
#undef G2STAGE

#pragma unroll
    for (int fn = 0; fn < 4; ++fn) {
        const int gn = n0 + fn*32 + lq;
        if (gn < DIMM) {
            const float bv = bias[gn];
#pragma unroll
            for (int r = 0; r < 16; ++r) {
                const int gm = m0 + w*32 + (r&3) + 8*(r>>2) + 4*lh;
                out[(size_t)gm*DIMM + gn] = acc[fn][r] + bv;
            }
        }
    }
}

// ---------------------------------------------------------------------------
extern "C" void kernel_launch(void* const* d_in, const int* in_sizes, int n_in,
                              void* d_out, int out_size, void* d_ws, size_t ws_size,
                              hipStream_t stream)
{
    const float* x    = (const float*)d_in[0];
    const float* wqv  = (const float*)d_in[1];
    const float* ek   = (const float*)d_in[2];
    const float* eb   = (const float*)d_in[3];
    const float* wout = (const float*)d_in[4];
    const float* bout = (const float*)d_in[5];
    float* out = (float*)d_out;

    const size_t MK = (size_t)MROWS*KDIM;        // 3,670,016
    const size_t EK = (size_t)NHEAD*NSEQ*HDIM;   // 458,752
    unsigned short* p = (unsigned short*)d_ws;
    unsigned short* xh    = p;  p += MK;
    unsigned short* wqvTh = p;  p += (size_t)896*KDIM;
    unsigned short* woTh  = p;  p += (size_t)512*KDIM;
    unsigned short* woTl  = p;  p += (size_t)512*KDIM;
    unsigned short* ekh   = p;  p += EK;
    unsigned short* qh    = p;  p += MK;
    unsigned short* vTh   = p;  p += MK;
    unsigned short* bpP   = p;  p += (size_t)NHEAD*NSEQ*NSEQ;  // fp16
    unsigned short* aoh   = p;  p += MK;
    unsigned short* aol   = p;  p += MK;

    cvt_single<<<MK/1024, 256, 0, stream>>>(x, xh);
    cvt_single<<<EK/1024, 256, 0, stream>>>(ek, ekh);
    wT_single<<<dim3(56, 14), 64, 0, stream>>>(wqv, wqvTh, 896);
    split_wT<<<dim3(56, 8), 64, 0, stream>>>(wout, woTh, woTl, DIMM);
    bias_prep<<<dim3(32, 16, 7), 128, 0, stream>>>(eb, bpP);

    gemm1<<<dim3(128, 7), 128, 0, stream>>>(xh, wqvTh, qh, vTh);
    attn2<<<dim3(16, NHEAD, BATCH), 128, 0, stream>>>(qh, vTh, ekh, bpP, aoh, aol);
    gemm2<<<dim3(128, 4), 128, 0, stream>>>(aoh, aol, woTh, woTl, bout, out);
}

// Round 6
// 200.617 us; speedup vs baseline: 1.2623x; 1.0496x over previous
//
#include <hip/hip_runtime.h>
#include <hip/hip_bf16.h>
#include <hip/hip_fp16.h>

#define BATCH 8
#define NSEQ 1024
#define DIMM 448
#define NHEAD 7
#define HDIM 64
#define MROWS (BATCH*NSEQ)   // 8192
#define KDIM 448
#define SCALE_F 0.125f

typedef short short8 __attribute__((ext_vector_type(8)));
typedef float floatx16 __attribute__((ext_vector_type(16)));

#define MFMA32(a,b,c) __builtin_amdgcn_mfma_f32_32x32x16_bf16(a,b,c,0,0,0)

__device__ __forceinline__ unsigned short f2bf(float f){
    __hip_bfloat16 h = __float2bfloat16(f);
    return *reinterpret_cast<unsigned short*>(&h);
}
__device__ __forceinline__ float bf2f(unsigned short u){
    __hip_bfloat16 h; *reinterpret_cast<unsigned short*>(&h) = u;
    return __bfloat162float(h);
}
__device__ __forceinline__ float h2f(unsigned short u){
    __half h; *reinterpret_cast<unsigned short*>(&h) = u;
    return __half2float(h);
}
__device__ __forceinline__ unsigned short f2h(float f){
    __half h = __float2half(f);
    return *reinterpret_cast<unsigned short*>(&h);
}

// ---------------------------------------------------------------------------
// prep_all: fused conversions (one launch).
//   [0,3584)      : x fp32 -> xh bf16 (1 float4/thread)
//   [3584,4032)   : ek fp32 -> ekh bf16
//   [4032,4228)   : wqv [448][896] -> wqvTh [896][448] bf16  (4x 64-thr units)
//   [4228,4340)   : wout [448][448] -> woTh/woTl [512][448] split bf16
//   [4340,6132)   : eb -> bp fp16, pre-scaled by 0.125, attn granule order
//                   (2x 128-thr units per block)
// bp layout: ((((h*16+qt)*32 + mt)*4 + g2*2 + jj)*512 + lane*8 + t) where
//   score q = qt*64 + g2*32 + (lane&31), m = mt*32 + (t&3)+8*(t>>2)+16*jj+4*(lane>>5)
// ---------------------------------------------------------------------------
__global__ __launch_bounds__(256)
void prep_all(const float* __restrict__ x, const float* __restrict__ ek,
              const float* __restrict__ wqv, const float* __restrict__ wout,
              const float* __restrict__ eb,
              unsigned short* __restrict__ xh, unsigned short* __restrict__ ekh,
              unsigned short* __restrict__ wqvTh, unsigned short* __restrict__ woTh,
              unsigned short* __restrict__ woTl, unsigned short* __restrict__ bp)
{
    __shared__ float T[2][64][33];
    const int bx = blockIdx.x, tid = threadIdx.x;

    if (bx < 3584) {                         // x -> bf16
        int i = bx*256 + tid;
        float4 v = ((const float4*)x)[i];
        ((ushort4*)xh)[i] = make_ushort4(f2bf(v.x), f2bf(v.y), f2bf(v.z), f2bf(v.w));
    } else if (bx < 4032) {                  // ek -> bf16
        int i = (bx-3584)*256 + tid;
        float4 v = ((const float4*)ek)[i];
        ((ushort4*)ekh)[i] = make_ushort4(f2bf(v.x), f2bf(v.y), f2bf(v.z), f2bf(v.w));
    } else if (bx < 4228) {                  // wqv transpose, single bf16
        int lid = (bx-4032)*4 + (tid>>6);    // 0..783 = kc(56) x ng(14)
        int kc = lid % 56, ng = lid / 56;
        int n = ng*64 + (tid&63);
        unsigned short h[8];
#pragma unroll
        for (int j = 0; j < 8; ++j) h[j] = f2bf(wqv[(size_t)(kc*8+j)*896 + n]);
        size_t o = (size_t)n*KDIM + kc*8;
        *(ushort4*)(wqvTh + o)     = make_ushort4(h[0],h[1],h[2],h[3]);
        *(ushort4*)(wqvTh + o + 4) = make_ushort4(h[4],h[5],h[6],h[7]);
    } else if (bx < 4340) {                  // wout transpose, split hi/lo
        int lid = (bx-4228)*4 + (tid>>6);    // 0..447 = kc(56) x ng(8)
        int kc = lid % 56, ng = lid / 56;
        int n = ng*64 + (tid&63);
        ushort4 h0={0,0,0,0}, h1={0,0,0,0}, l0={0,0,0,0}, l1={0,0,0,0};
        if (n < DIMM) {
            unsigned short h[8], l[8];
#pragma unroll
            for (int j = 0; j < 8; ++j) {
                float f = wout[(size_t)(kc*8+j)*DIMM + n];
                h[j] = f2bf(f); l[j] = f2bf(f - bf2f(h[j]));
            }
            h0 = make_ushort4(h[0],h[1],h[2],h[3]); h1 = make_ushort4(h[4],h[5],h[6],h[7]);
            l0 = make_ushort4(l[0],l[1],l[2],l[3]); l1 = make_ushort4(l[4],l[5],l[6],l[7]);
        }
        size_t o = (size_t)n*KDIM + kc*8;
        *(ushort4*)(woTh + o) = h0; *(ushort4*)(woTh + o + 4) = h1;
        *(ushort4*)(woTl + o) = l0; *(ushort4*)(woTl + o + 4) = l1;
    } else {                                 // bias prep
        const int sub = tid >> 7, st = tid & 127;
        const int lid = (bx-4340)*2 + sub;   // 0..3583
        const int mt = lid & 31, qt = (lid>>5) & 15, h = lid >> 9;
#pragma unroll
        for (int it = 0; it < 4; ++it) {
            int idx = it*128 + st;
            int row = idx >> 3, c4 = (idx & 7)*4;
            float4 v = *(const float4*)(eb + ((size_t)(h*NSEQ + qt*64 + row))*NSEQ + mt*32 + c4);
            T[sub][row][c4+0]=v.x; T[sub][row][c4+1]=v.y;
            T[sub][row][c4+2]=v.z; T[sub][row][c4+3]=v.w;
        }
        __syncthreads();
        const int g2 = st >> 6, lane = st & 63;
        const int lq = lane & 31, quad = lane >> 5;
        const int q = g2*32 + lq;
        unsigned short* dst = bp + ((((size_t)h*16 + qt)*32 + mt)*4 + g2*2)*512 + lane*8;
#pragma unroll
        for (int jj = 0; jj < 2; ++jj) {
            unsigned short o[8];
#pragma unroll
            for (int t = 0; t < 8; ++t) {
                int m = (t&3) + 8*(t>>2) + 16*jj + 4*quad;
                o[t] = f2h(T[sub][q][m] * SCALE_F);
            }
            *(ushort4*)(dst + jj*512)     = make_ushort4(o[0],o[1],o[2],o[3]);
            *(ushort4*)(dst + jj*512 + 4) = make_ushort4(o[4],o[5],o[6],o[7]);
        }
    }
}

// ---------------------------------------------------------------------------
// gemm1_reg: qv = x @ w_qv, single bf16, REGISTER-ONLY (no LDS, no barriers).
// 1 wave per block, tile 64x64, BK=32, depth-1 reg prefetch.
// grid (128, 14), block 64. y<7 -> q heads; y>=7 -> vT heads (transposed).
// ---------------------------------------------------------------------------
__global__ __launch_bounds__(64, 2)
void gemm1_reg(const unsigned short* __restrict__ Ah, const unsigned short* __restrict__ Bh,
               unsigned short* __restrict__ qd, unsigned short* __restrict__ vTd)
{
    const int lane = threadIdx.x;
    const int lq = lane & 31, lh = lane >> 5;
    const int m0 = blockIdx.x * 64;
    const int y  = blockIdx.y;
    const int n0 = y * 64;
    const unsigned short* aB = Ah + (size_t)(m0 + lq)*KDIM + lh*8;
    const unsigned short* bB = Bh + (size_t)(n0 + lq)*KDIM + lh*8;

    floatx16 acc[2][2] = {};
    short8 aR[2][2][2], bR[2][2][2];
#define LD1(kt, par) {                                                        \
    _Pragma("unroll") for (int fm = 0; fm < 2; ++fm)                          \
    _Pragma("unroll") for (int c = 0; c < 2; ++c) {                           \
        aR[par][fm][c] = *(const short8*)(aB + (size_t)fm*32*KDIM + (kt)*32 + c*16); \
        bR[par][fm][c] = *(const short8*)(bB + (size_t)fm*32*KDIM + (kt)*32 + c*16); } }

    LD1(0, 0)
#pragma unroll
    for (int kt = 0; kt < 14; ++kt) {
        const int par = kt & 1;
        if (kt < 13) LD1(kt+1, par^1)
#pragma unroll
        for (int c = 0; c < 2; ++c)
#pragma unroll
            for (int fm = 0; fm < 2; ++fm)
#pragma unroll
                for (int fn = 0; fn < 2; ++fn)
                    acc[fm][fn] = MFMA32(aR[par][fm][c], bR[par][fn][c], acc[fm][fn]);
    }
#undef LD1

    if (y < NHEAD) {
#pragma unroll
        for (int fm = 0; fm < 2; ++fm)
#pragma unroll
            for (int fn = 0; fn < 2; ++fn) {
                const int d = fn*32 + lq;
#pragma unroll
                for (int r = 0; r < 16; ++r) {
                    const int gm = m0 + fm*32 + (r&3) + 8*(r>>2) + 4*lh;
                    const int b = gm >> 10, ns = gm & 1023;
                    qd[((size_t)((b*NHEAD + y)*NSEQ + ns))*HDIM + d] = f2bf(acc[fm][fn][r]);
                }
            }
    } else {
        const int head = y - NHEAD;
#pragma unroll
        for (int fm = 0; fm < 2; ++fm)
#pragma unroll
            for (int fn = 0; fn < 2; ++fn) {
                const int d = fn*32 + lq;
#pragma unroll
                for (int r = 0; r < 16; ++r) {
                    const int gm = m0 + fm*32 + (r&3) + 8*(r>>2) + 4*lh;
                    const int b = gm >> 10, ns = gm & 1023;
                    vTd[((size_t)((b*NHEAD + head)*HDIM + d))*NSEQ + ns] = f2bf(acc[fm][fn][r]);
                }
            }
    }
}

// ---------------------------------------------------------------------------
// attn4: barrier-free flash attention. 1 wave/block, 64 q-rows.
// K/V/bias prefetched to REGISTERS (depth-1 ping-pong); LDS only for the
// wave-private P transpose (2KB) + l transpose (256B) — no __syncthreads.
// Q/K/V/P single bf16, bias fp16 pre-scaled, no-max softmax (scores bounded).
// grid (16 qt, 7 h, 8 b), block 64.
// ---------------------------------------------------------------------------
__global__ __launch_bounds__(64, 2)
void attn4(const unsigned short* __restrict__ qh_g, const unsigned short* __restrict__ vTh,
           const unsigned short* __restrict__ ekh, const unsigned short* __restrict__ bp,
           unsigned short* __restrict__ aoh, unsigned short* __restrict__ aol)
{
    __shared__ unsigned short pS[1024];
    __shared__ float linv[2][32];

    const int lane = threadIdx.x;
    const int lq = lane & 31, lh = lane >> 5;
    const int qt = blockIdx.x, head = blockIdx.y, b = blockIdx.z;
    const int bh = b*NHEAD + head;

    short8 qf[2][4];
#pragma unroll
    for (int g2 = 0; g2 < 2; ++g2)
#pragma unroll
        for (int c = 0; c < 4; ++c)
            qf[g2][c] = *(const short8*)(qh_g +
                ((size_t)(bh*NSEQ) + qt*64 + g2*32 + lq)*HDIM + c*16 + lh*8);

    const unsigned short* kB = ekh + ((size_t)head*NSEQ + lq)*HDIM + lh*8;
    const unsigned short* vB = vTh + ((size_t)(bh*HDIM) + lq)*NSEQ;
    const unsigned short* bB = bp + ((size_t)(head*16 + qt))*65536 + lane*8;

    short8 kR[2][4], vR[2][4], bR[2][4];
#define PREF(J, par) { const int mm = ((J) < 32) ? (J) : 0;                    \
    _Pragma("unroll") for (int c = 0; c < 4; ++c)                              \
        kR[par][c] = *(const short8*)(kB + (size_t)mm*2048 + c*16);            \
    _Pragma("unroll") for (int c2 = 0; c2 < 2; ++c2)                           \
    _Pragma("unroll") for (int h2 = 0; h2 < 2; ++h2)                           \
        vR[par][c2*2+h2] = *(const short8*)(vB + (size_t)(h2*32)*NSEQ + mm*32 + (c2*2+lh)*8); \
    _Pragma("unroll") for (int u = 0; u < 4; ++u)                              \
        bR[par][u] = *(const short8*)(bB + ((size_t)mm*4 + u)*512); }

    floatx16 O[2][2] = {};
    float ls[2] = {0.f, 0.f};

#define SEC(J, par, nxt) {                                                     \
    PREF((J)+1, nxt)                                                           \
    _Pragma("unroll") for (int g2 = 0; g2 < 2; ++g2) {                         \
        floatx16 S = {};                                                       \
        _Pragma("unroll") for (int c = 0; c < 4; ++c)                          \
            S = MFMA32(kR[par][c], qf[g2][c], S);                              \
        _Pragma("unroll") for (int g = 0; g < 4; ++g) {                        \
            unsigned short hb[4];                                              \
            _Pragma("unroll") for (int j2 = 0; j2 < 4; ++j2) {                 \
                const int i = g*4 + j2;                                        \
                float bs = h2f((unsigned short)bR[par][g2*2 + (i>>3)][i&7]);   \
                float pv = __expf(fmaf(S[i], SCALE_F, bs));                    \
                ls[g2] += pv;  hb[j2] = f2bf(pv);                              \
            }                                                                  \
            *(ushort4*)(pS + g*256 + lq*8 + lh*4) = make_ushort4(hb[0],hb[1],hb[2],hb[3]); \
        }                                                                      \
        _Pragma("unroll") for (int c2 = 0; c2 < 2; ++c2) {                     \
            short8 pf = *(const short8*)(pS + ((c2*2+lh)*32 + lq)*8);          \
            O[g2][0] = MFMA32(pf, vR[par][c2*2+0], O[g2][0]);                  \
            O[g2][1] = MFMA32(pf, vR[par][c2*2+1], O[g2][1]);                  \
        } } }

    PREF(0, 0)
    for (int jj = 0; jj < 16; ++jj) {
        SEC(2*jj,   0, 1)
        SEC(2*jj+1, 1, 0)
    }
#undef SEC
#undef PREF

    // l: partial per lane-column -> full via lh-partner, transpose via LDS
    float lt0 = ls[0] + __shfl_xor(ls[0], 32);
    float lt1 = ls[1] + __shfl_xor(ls[1], 32);
    if (lh == 0) { linv[0][lq] = 1.f/lt0; linv[1][lq] = 1.f/lt1; }

#pragma unroll
    for (int g2 = 0; g2 < 2; ++g2)
#pragma unroll
        for (int r = 0; r < 16; ++r) {
            const int qr = (r&3) + 8*(r>>2) + 4*lh;
            const float inv = linv[g2][qr];
            const size_t o = ((size_t)(b*NSEQ) + qt*64 + g2*32 + qr)*DIMM + head*HDIM + lq;
            float v0 = O[g2][0][r]*inv, v1 = O[g2][1][r]*inv;
            unsigned short h0 = f2bf(v0), h1 = f2bf(v1);
            aoh[o]      = h0;  aol[o]      = f2bf(v0 - bf2f(h0));
            aoh[o + 32] = h1;  aol[o + 32] = f2bf(v1 - bf2f(h1));
        }
}

// ---------------------------------------------------------------------------
// gemm2_reg: out = ao @ w_out + b_out, split-2 (3-term), REGISTER-ONLY.
// 1 wave/block, tile 64x64, BK=32, depth-1 reg prefetch. grid (128, 7).
// ---------------------------------------------------------------------------
__global__ __launch_bounds__(64, 2)
void gemm2_reg(const unsigned short* __restrict__ Ah, const unsigned short* __restrict__ Al,
               const unsigned short* __restrict__ Bh, const unsigned short* __restrict__ Bl,
               const float* __restrict__ bias, float* __restrict__ out)
{
    const int lane = threadIdx.x;
    const int lq = lane & 31, lh = lane >> 5;
    const int m0 = blockIdx.x * 64;
    const int n0 = blockIdx.y * 64;
    const unsigned short* aBh = Ah + (size_t)(m0 + lq)*KDIM + lh*8;
    const unsigned short* aBl = Al + (size_t)(m0 + lq)*KDIM + lh*8;
    const unsigned short* bBh = Bh + (size_t)(n0 + lq)*KDIM + lh*8;
    const unsigned short* bBl = Bl + (size_t)(n0 + lq)*KDIM + lh*8;

    floatx16 acc[2][2] = {};
    short8 aH[2][2][2], aL[2][2][2], bH[2][2][2], bL[2][2][2];
#define LD2(kt, par) {                                                        \
    _Pragma("unroll") for (int fm = 0; fm < 2; ++fm)                          \
    _Pragma("unroll") for (int c = 0; c < 2; ++c) {                           \
        const size_t off = (size_t)fm*32*KDIM + (kt)*32 + c*16;               \
        aH[par][fm][c] = *(const short8*)(aBh + off);                         \
        aL[par][fm][c] = *(const short8*)(aBl + off);                         \
        bH[par][fm][c] = *(const short8*)(bBh + off);                         \
        bL[par][fm][c] = *(const short8*)(bBl + off); } }

    LD2(0, 0)
#pragma unroll
    for (int kt = 0; kt < 14; ++kt) {
        const int par = kt & 1;
        if (kt < 13) LD2(kt+1, par^1)
#pragma unroll
        for (int c = 0; c < 2; ++c)
#pragma unroll
            for (int fm = 0; fm < 2; ++fm)
#pragma unroll
                for (int fn = 0; fn < 2; ++fn) {
                    acc[fm][fn] = MFMA32(aH[par][fm][c], bH[par][fn][c], acc[fm][fn]);
                    acc[fm][fn] = MFMA32(aL[par][fm][c], bH[par][fn][c], acc[fm][fn]);
                    acc[fm][fn] = MFMA32(aH[par][fm][c], bL[par][fn][c], acc[fm][fn]);
                }
    }
#undef LD2

#pragma unroll
    for (int fm = 0; fm < 2; ++fm)
#pragma unroll
        for (int fn = 0; fn < 2; ++fn) {
            const int gn = n0 + fn*32 + lq;
            const float bv = bias[gn];
#pragma unroll
            for (int r = 0; r < 16; ++r) {
                const int gm = m0 + fm*32 + (r&3) + 8*(r>>2) + 4*lh;
                out[(size_t)gm*DIMM + gn] = acc[fm][fn][r] + bv;
            }
        }
}

// ---------------------------------------------------------------------------
extern "C" void kernel_launch(void* const* d_in, const int* in_sizes, int n_in,
                              void* d_out, int out_size, void* d_ws, size_t ws_size,
                              hipStream_t stream)
{
    const float* x    = (const float*)d_in[0];
    const float* wqv  = (const float*)d_in[1];
    const float* ek   = (const float*)d_in[2];
    const float* eb   = (const float*)d_in[3];
    const float* wout = (const float*)d_in[4];
    const float* bout = (const float*)d_in[5];
    float* out = (float*)d_out;

    const size_t MK = (size_t)MROWS*KDIM;        // 3,670,016
    const size_t EK = (size_t)NHEAD*NSEQ*HDIM;   // 458,752
    unsigned short* p = (unsigned short*)d_ws;
    unsigned short* xh    = p;  p += MK;
    unsigned short* wqvTh = p;  p += (size_t)896*KDIM;
    unsigned short* woTh  = p;  p += (size_t)512*KDIM;
    unsigned short* woTl  = p;  p += (size_t)512*KDIM;
    unsigned short* ekh   = p;  p += EK;
    unsigned short* qh    = p;  p += MK;
    unsigned short* vTh   = p;  p += MK;
    unsigned short* bp    = p;  p += (size_t)NHEAD*NSEQ*NSEQ;  // fp16
    unsigned short* aoh   = p;  p += MK;
    unsigned short* aol   = p;  p += MK;

    prep_all<<<6132, 256, 0, stream>>>(x, ek, wqv, wout, eb,
                                       xh, ekh, wqvTh, woTh, woTl, bp);
    gemm1_reg<<<dim3(128, 14), 64, 0, stream>>>(xh, wqvTh, qh, vTh);
    attn4<<<dim3(16, NHEAD, BATCH), 64, 0, stream>>>(qh, vTh, ekh, bp, aoh, aol);
    gemm2_reg<<<dim3(128, 7), 64, 0, stream>>>(aoh, aol, woTh, woTl, bout, out);
}